// Round 4
// baseline (175.124 us; speedup 1.0000x reference)
//
#include <hip/hip_runtime.h>
#include <math.h>

#define BB 256
#define L 512
#define NSIG 50

__device__ __forceinline__ int refl(int i) {
    if (i < 0) i = -i;
    if (i >= L) i = 2 * L - 2 - i;
    return i;
}

__device__ __forceinline__ float selu(float x) {
    const float scale = 1.0507009873554804934193349852946f;
    const float alpha = 1.6732632423543772848170429916717f;
    return x > 0.f ? scale * x : scale * alpha * (__expf(x) - 1.f);
}

// ---------------- Kernel A: sharedCNN x2 + residual + LayerNorm ----------------
__global__ __launch_bounds__(256) void shared_ln_kernel(
    const float* __restrict__ latent,   // (B, 2048)
    const float* __restrict__ w1, const float* __restrict__ b1,   // (8,4,5),(8,)
    const float* __restrict__ w2, const float* __restrict__ b2,   // (4,8,5),(4,)
    const float* __restrict__ g,  const float* __restrict__ beta, // (512,),(512,)
    float* __restrict__ D)              // (B,4,512)
{
    __shared__ float xb[4][L];
    __shared__ float hb[8][L];
    __shared__ float yb[4][L];
    __shared__ float sw1[160], sb1[8], sw2[160], sb2[4];

    const int b = blockIdx.x;
    const int t = threadIdx.x;

    for (int i = t; i < 160; i += 256) { sw1[i] = w1[i]; sw2[i] = w2[i]; }
    if (t < 8) sb1[t] = b1[t];
    if (t < 4) sb2[t] = b2[t];

    const float* lp = latent + (size_t)b * 2048;
    for (int i = t; i < 2048; i += 256)
        xb[i & 3][i >> 2] = lp[i];   // x[c][l] = latent[l*4+c]
    __syncthreads();

    for (int pass = 0; pass < 2; ++pass) {
        const float (*src)[L] = (pass == 0) ? (const float (*)[L])xb
                                            : (const float (*)[L])yb;
        // conv1: 4->8, k5, d1, pad2, SELU
        for (int idx = t; idx < 8 * L; idx += 256) {
            int co = idx >> 9, l = idx & (L - 1);
            float acc = sb1[co];
            #pragma unroll
            for (int ci = 0; ci < 4; ++ci) {
                const float* w = &sw1[(co * 4 + ci) * 5];
                #pragma unroll
                for (int k = 0; k < 5; ++k)
                    acc += w[k] * src[ci][refl(l + k - 2)];
            }
            hb[co][l] = selu(acc);
        }
        __syncthreads();
        // conv2: 8->4, k5, d2, pad4 (+ residual on pass 1)
        for (int idx = t; idx < 4 * L; idx += 256) {
            int co = idx >> 9, l = idx & (L - 1);
            float acc = sb2[co];
            #pragma unroll
            for (int ci = 0; ci < 8; ++ci) {
                const float* w = &sw2[(co * 8 + ci) * 5];
                #pragma unroll
                for (int k = 0; k < 5; ++k)
                    acc += w[k] * hb[ci][refl(l + 2 * k - 4)];
            }
            if (pass == 1) acc += xb[co][l];
            yb[co][l] = acc;
        }
        __syncthreads();
    }

    // LayerNorm over length axis, one wave per channel (4 waves = 256 threads)
    const int wave = t >> 6;    // channel 0..3
    const int lane = t & 63;
    float v[8];
    float s = 0.f;
    #pragma unroll
    for (int j = 0; j < 8; ++j) { v[j] = yb[wave][lane * 8 + j]; s += v[j]; }
    #pragma unroll
    for (int off = 32; off > 0; off >>= 1) s += __shfl_down(s, off);
    s = __shfl(s, 0);
    const float mu = s * (1.f / 512.f);
    float s2 = 0.f;
    #pragma unroll
    for (int j = 0; j < 8; ++j) { float d = v[j] - mu; s2 += d * d; }
    #pragma unroll
    for (int off = 32; off > 0; off >>= 1) s2 += __shfl_down(s2, off);
    s2 = __shfl(s2, 0);
    const float rinv = rsqrtf(s2 * (1.f / 512.f) + 1e-10f);

    float* Dp = D + ((size_t)b * 4 + wave) * L;
    #pragma unroll
    for (int j = 0; j < 8; ++j) {
        int l = lane * 8 + j;
        Dp[l] = (v[j] - mu) * rinv * g[l] + beta[l];
    }
}

// ---------------- Kernel B: per-signal channel-reduction stack ----------------
// ZERO-LDS version. One wave = one (b, s); lane owns 8 positions (p0=lane*8).
// All intermediates in registers; conv halos via __shfl_up/down(.,1) with
// reflect fixed by lane 0/63 selects. Weights via readfirstlane-uniform
// pointers -> pure s_load (SGPR operand in v_fmac).
__global__ __launch_bounds__(128) void signal_kernel(
    const float* __restrict__ D,   // (B,4,512)
    const float* __restrict__ w1, const float* __restrict__ b1, // (50,8,4,7),(50,8)
    const float* __restrict__ w2, const float* __restrict__ b2, // (50,4,8,5),(50,4)
    const float* __restrict__ w3, const float* __restrict__ b3, // (50,2,4,5),(50,2)
    const float* __restrict__ w4, const float* __restrict__ b4, // (50,1,2,5),(50,1)
    float* __restrict__ out)       // (B,50,512)
{
    const int lane = threadIdx.x & 63;
    const int s = __builtin_amdgcn_readfirstlane(blockIdx.x * 2 + (threadIdx.x >> 6));
    const int b = blockIdx.y;
    const int p0 = lane * 8;

    const float* W1 = w1 + s * 224; const float* B1 = b1 + s * 8;
    const float* W2 = w2 + s * 160; const float* B2 = b2 + s * 4;
    const float* W3 = w3 + s * 40;  const float* B3 = b3 + s * 2;
    const float* W4 = w4 + s * 10;  const float  B4 = b4[s];

    // ---- preload own D values: din[ci][0..7] ----
    float din[4][8];
    #pragma unroll
    for (int ci = 0; ci < 4; ++ci) {
        const float* Dp = D + ((size_t)b * 4 + ci) * L + p0;
        *(float4*)&din[ci][0] = *(const float4*)Dp;
        *(float4*)&din[ci][4] = *(const float4*)(Dp + 4);
    }

    // ---- conv1: 4->8, k7, pad3 (no activation) ----
    float h1[8][8];
    #pragma unroll
    for (int co = 0; co < 8; ++co) {
        float bb = B1[co];
        #pragma unroll
        for (int p = 0; p < 8; ++p) h1[co][p] = bb;
    }
    #pragma unroll
    for (int ci = 0; ci < 4; ++ci) {
        const float* o = din[ci];
        float x[14];
        float l0 = __shfl_up(o[7], 1);   if (lane == 0)  l0 = o[1]; // p0-1
        float l1 = __shfl_up(o[6], 1);   if (lane == 0)  l1 = o[2]; // p0-2
        float l2 = __shfl_up(o[5], 1);   if (lane == 0)  l2 = o[3]; // p0-3
        float r0 = __shfl_down(o[0], 1); if (lane == 63) r0 = o[6]; // p0+8
        float r1 = __shfl_down(o[1], 1); if (lane == 63) r1 = o[5]; // p0+9
        float r2 = __shfl_down(o[2], 1); if (lane == 63) r2 = o[4]; // p0+10
        x[0] = l2; x[1] = l1; x[2] = l0;
        #pragma unroll
        for (int j = 0; j < 8; ++j) x[3 + j] = o[j];
        x[11] = r0; x[12] = r1; x[13] = r2;
        #pragma unroll
        for (int co = 0; co < 8; ++co)
            #pragma unroll
            for (int k = 0; k < 7; ++k) {
                float w = W1[(co * 4 + ci) * 7 + k];
                #pragma unroll
                for (int p = 0; p < 8; ++p)
                    h1[co][p] += w * x[p + k];
            }
    }

    // ---- conv2: 8->4, k5, pad2, SELU ----
    float h2[4][8];
    #pragma unroll
    for (int co = 0; co < 4; ++co) {
        float bb = B2[co];
        #pragma unroll
        for (int p = 0; p < 8; ++p) h2[co][p] = bb;
    }
    #pragma unroll
    for (int ci = 0; ci < 8; ++ci) {
        const float* o = h1[ci];
        float x[12];
        float l0 = __shfl_up(o[7], 1);   if (lane == 0)  l0 = o[1]; // p0-1
        float l1 = __shfl_up(o[6], 1);   if (lane == 0)  l1 = o[2]; // p0-2
        float r0 = __shfl_down(o[0], 1); if (lane == 63) r0 = o[6]; // p0+8
        float r1 = __shfl_down(o[1], 1); if (lane == 63) r1 = o[5]; // p0+9
        x[0] = l1; x[1] = l0;
        #pragma unroll
        for (int j = 0; j < 8; ++j) x[2 + j] = o[j];
        x[10] = r0; x[11] = r1;
        #pragma unroll
        for (int co = 0; co < 4; ++co)
            #pragma unroll
            for (int k = 0; k < 5; ++k) {
                float w = W2[(co * 8 + ci) * 5 + k];
                #pragma unroll
                for (int p = 0; p < 8; ++p)
                    h2[co][p] += w * x[p + k];
            }
    }
    #pragma unroll
    for (int co = 0; co < 4; ++co)
        #pragma unroll
        for (int p = 0; p < 8; ++p)
            h2[co][p] = selu(h2[co][p]);

    // ---- conv3: 4->2, k5, pad2 (no activation) ----
    float h3[2][8];
    #pragma unroll
    for (int co = 0; co < 2; ++co) {
        float bb = B3[co];
        #pragma unroll
        for (int p = 0; p < 8; ++p) h3[co][p] = bb;
    }
    #pragma unroll
    for (int ci = 0; ci < 4; ++ci) {
        const float* o = h2[ci];
        float x[12];
        float l0 = __shfl_up(o[7], 1);   if (lane == 0)  l0 = o[1];
        float l1 = __shfl_up(o[6], 1);   if (lane == 0)  l1 = o[2];
        float r0 = __shfl_down(o[0], 1); if (lane == 63) r0 = o[6];
        float r1 = __shfl_down(o[1], 1); if (lane == 63) r1 = o[5];
        x[0] = l1; x[1] = l0;
        #pragma unroll
        for (int j = 0; j < 8; ++j) x[2 + j] = o[j];
        x[10] = r0; x[11] = r1;
        #pragma unroll
        for (int co = 0; co < 2; ++co)
            #pragma unroll
            for (int k = 0; k < 5; ++k) {
                float w = W3[(co * 4 + ci) * 5 + k];
                #pragma unroll
                for (int p = 0; p < 8; ++p)
                    h3[co][p] += w * x[p + k];
            }
    }

    // ---- conv4: 2->1, k5, d2, pad4, SELU ----
    float acc[8];
    #pragma unroll
    for (int p = 0; p < 8; ++p) acc[p] = B4;
    #pragma unroll
    for (int ci = 0; ci < 2; ++ci) {
        const float* o = h3[ci];
        float x[16];
        float l0 = __shfl_up(o[7], 1);   if (lane == 0)  l0 = o[1]; // p0-1
        float l1 = __shfl_up(o[6], 1);   if (lane == 0)  l1 = o[2]; // p0-2
        float l2 = __shfl_up(o[5], 1);   if (lane == 0)  l2 = o[3]; // p0-3
        float l3 = __shfl_up(o[4], 1);   if (lane == 0)  l3 = o[4]; // p0-4
        float r0 = __shfl_down(o[0], 1); if (lane == 63) r0 = o[6]; // 512
        float r1 = __shfl_down(o[1], 1); if (lane == 63) r1 = o[5]; // 513
        float r2 = __shfl_down(o[2], 1); if (lane == 63) r2 = o[4]; // 514
        float r3 = __shfl_down(o[3], 1); if (lane == 63) r3 = o[3]; // 515
        x[0] = l3; x[1] = l2; x[2] = l1; x[3] = l0;
        #pragma unroll
        for (int j = 0; j < 8; ++j) x[4 + j] = o[j];
        x[12] = r0; x[13] = r1; x[14] = r2; x[15] = r3;
        #pragma unroll
        for (int k = 0; k < 5; ++k) {
            float w = W4[ci * 5 + k];
            #pragma unroll
            for (int p = 0; p < 8; ++p)
                acc[p] += w * x[p + 2 * k];
        }
    }
    float4 o0 = { selu(acc[0]), selu(acc[1]), selu(acc[2]), selu(acc[3]) };
    float4 o1 = { selu(acc[4]), selu(acc[5]), selu(acc[6]), selu(acc[7]) };
    float* op = &out[((size_t)b * NSIG + s) * L + p0];
    *(float4*)op = o0;
    *(float4*)(op + 4) = o1;
}

extern "C" void kernel_launch(void* const* d_in, const int* in_sizes, int n_in,
                              void* d_out, int out_size, void* d_ws, size_t ws_size,
                              hipStream_t stream) {
    const float* latent = (const float*)d_in[0];
    const float* sw1 = (const float*)d_in[1];
    const float* sb1 = (const float*)d_in[2];
    const float* sw2 = (const float*)d_in[3];
    const float* sb2 = (const float*)d_in[4];
    const float* ln_g = (const float*)d_in[5];
    const float* ln_b = (const float*)d_in[6];
    const float* g_w1 = (const float*)d_in[7];
    const float* g_b1 = (const float*)d_in[8];
    const float* g_w2 = (const float*)d_in[9];
    const float* g_b2 = (const float*)d_in[10];
    const float* g_w3 = (const float*)d_in[11];
    const float* g_b3 = (const float*)d_in[12];
    const float* g_w4 = (const float*)d_in[13];
    const float* g_b4 = (const float*)d_in[14];
    float* out = (float*)d_out;
    float* D = (float*)d_ws;   // (256,4,512) f32 = 2 MB

    shared_ln_kernel<<<BB, 256, 0, stream>>>(latent, sw1, sb1, sw2, sb2,
                                             ln_g, ln_b, D);
    signal_kernel<<<dim3(NSIG / 2, BB), 128, 0, stream>>>(D, g_w1, g_b1, g_w2, g_b2,
                                                          g_w3, g_b3, g_w4, g_b4, out);
}